// Round 1
// baseline (382.113 us; speedup 1.0000x reference)
//
#include <hip/hip_runtime.h>
#include <stdint.h>

#define K_TOP 10000
#define CAP   16384
#define N0    98304
#define N1    24576
#define N2    6144
#define N3    1536
#define N4    384
#define NROWS (K_TOP + K_TOP + N2 + N3 + N4)   // 28064
#define MAXGT 2048

struct SelState {
    unsigned hist[2][256];
    unsigned prefix[2];
    unsigned remK[2];
    unsigned candCount[2];
};

struct Ptrs {
    const float* anc[5];
    const float* cls[5];
    const float* reg[5];
};

// order-preserving float->uint map (ascending uint == ascending float)
__device__ __forceinline__ unsigned f2ord(float f) {
    unsigned u = __float_as_uint(f);
    return (u & 0x80000000u) ? ~u : (u | 0x80000000u);
}

__global__ void k_init(SelState* st) {
    int t = threadIdx.x;
    st->hist[0][t] = 0;
    st->hist[1][t] = 0;
    if (t < 2) { st->prefix[t] = 0; st->remK[t] = K_TOP; st->candCount[t] = 0; }
}

__global__ void k_hist(const float* __restrict__ cls0, const float* __restrict__ cls1,
                       SelState* st, int pass) {
    int lev = blockIdx.y;
    const float* cls = lev ? cls1 : cls0;
    int n = lev ? N1 : N0;
    __shared__ unsigned lh[256];
    lh[threadIdx.x] = 0;
    __syncthreads();
    unsigned prefix = st->prefix[lev];
    unsigned maskAbove = (pass == 0) ? 0u : (0xFFFFFFFFu << (32 - 8 * pass));
    int shift = 24 - 8 * pass;
    for (int i = blockIdx.x * blockDim.x + threadIdx.x; i < n; i += gridDim.x * blockDim.x) {
        unsigned key = f2ord(cls[i]);
        if ((key & maskAbove) == prefix)
            atomicAdd(&lh[(key >> shift) & 0xFFu], 1u);
    }
    __syncthreads();
    if (lh[threadIdx.x]) atomicAdd(&st->hist[lev][threadIdx.x], lh[threadIdx.x]);
}

__global__ void k_pick(SelState* st, int pass) {
    int lev = blockIdx.x;
    int t = threadIdx.x;
    __shared__ unsigned h[256];
    h[t] = st->hist[lev][t];
    st->hist[lev][t] = 0;           // reset for next pass
    __syncthreads();
    unsigned cum = 0;               // count of elements with digit > t (matching prefix)
    for (int e = t + 1; e < 256; e++) cum += h[e];
    unsigned remK = st->remK[lev];
    if (cum < remK && cum + h[t] >= remK) {   // unique digit
        st->remK[lev] = remK - cum;
        st->prefix[lev] |= ((unsigned)t) << (24 - 8 * pass);
    }
}

__global__ void k_compact(const float* __restrict__ cls0, const float* __restrict__ cls1,
                          SelState* st, unsigned long long* __restrict__ cand) {
    int lev = blockIdx.y;
    const float* cls = lev ? cls1 : cls0;
    int n = lev ? N1 : N0;
    unsigned T = st->prefix[lev];   // K-th largest key
    for (int i = blockIdx.x * blockDim.x + threadIdx.x; i < n; i += gridDim.x * blockDim.x) {
        unsigned key = f2ord(cls[i]);
        if (key >= T) {
            unsigned slot = atomicAdd(&st->candCount[lev], 1u);
            if (slot < CAP)
                cand[(size_t)lev * CAP + slot] =
                    ((unsigned long long)key << 32) | (unsigned)(~(unsigned)i);
        }
    }
}

__global__ void k_rank(SelState* st, const unsigned long long* __restrict__ cand,
                       unsigned* __restrict__ selIdx) {
    int lev = blockIdx.y;
    unsigned cnt = st->candCount[lev];
    if (cnt > CAP) cnt = CAP;
    int i = blockIdx.x * blockDim.x + threadIdx.x;
    unsigned long long ci = 0ull;
    if (i < (int)cnt) ci = cand[(size_t)lev * CAP + i];
    unsigned rank = 0;
    __shared__ unsigned long long tile[256];
    for (unsigned base = 0; base < cnt; base += 256) {
        unsigned j = base + threadIdx.x;
        tile[threadIdx.x] = (j < cnt) ? cand[(size_t)lev * CAP + j] : 0ull;
        __syncthreads();
        unsigned lim = (cnt - base < 256u) ? (cnt - base) : 256u;
        if (i < (int)cnt) {
            for (unsigned t = 0; t < lim; t++) rank += (tile[t] > ci) ? 1u : 0u;
        }
        __syncthreads();
    }
    if (i < (int)cnt && rank < K_TOP)
        selIdx[lev * K_TOP + rank] = ~(unsigned)ci;   // original index
}

__global__ void __launch_bounds__(256)
k_final(Ptrs p, const float* __restrict__ gt, const int* __restrict__ numgt,
        const unsigned* __restrict__ selIdx, float* __restrict__ out) {
    __shared__ float4 sg[MAXGT];
    __shared__ float sarea[MAXGT];
    int ng = *numgt;
    if (ng > MAXGT) ng = MAXGT;
    for (int g = threadIdx.x; g < ng; g += blockDim.x) {
        float x1 = gt[g * 5 + 0], y1 = gt[g * 5 + 1];
        float x2 = gt[g * 5 + 2], y2 = gt[g * 5 + 3];
        sg[g] = make_float4(x1, y1, x2, y2);
        sarea[g] = (x2 - x1 + 1.0f) * (y2 - y1 + 1.0f);
    }
    __syncthreads();
    int r = blockIdx.x * blockDim.x + threadIdx.x;
    if (r >= NROWS) return;

    int lev, ai;
    if (r < K_TOP)                  { lev = 0; ai = (int)selIdx[r]; }
    else if (r < 2 * K_TOP)         { lev = 1; ai = (int)selIdx[r]; }  // selIdx[K_TOP + (r-K_TOP)]
    else if (r < 2 * K_TOP + N2)    { lev = 2; ai = r - 2 * K_TOP; }
    else if (r < 2 * K_TOP + N2 + N3) { lev = 3; ai = r - (2 * K_TOP + N2); }
    else                            { lev = 4; ai = r - (2 * K_TOP + N2 + N3); }

    const float* A = p.anc[lev];
    const float* C = p.cls[lev];
    const float* R = p.reg[lev];

    float ax1 = A[ai * 4 + 0], ay1 = A[ai * 4 + 1];
    float ax2 = A[ai * 4 + 2], ay2 = A[ai * 4 + 3];
    float score = 1.0f / (1.0f + expf(-C[ai]));
    float d0 = R[ai * 8 + 0], d1 = R[ai * 8 + 1];
    float d2 = R[ai * 8 + 2], d3 = R[ai * 8 + 3];

    float w = ax2 - ax1 + 1.0f, h = ay2 - ay1 + 1.0f;
    float cx = ax1 + 0.5f * w,  cy = ay1 + 0.5f * h;
    float pcx = d0 * w + cx,    pcy = d1 * h + cy;
    float pw = expf(d2) * w,    ph = expf(d3) * h;
    float bx1 = pcx - 0.5f * pw, by1 = pcy - 0.5f * ph;
    float bx2 = pcx + 0.5f * pw - 1.0f, by2 = pcy + 0.5f * ph - 1.0f;

    float areaA = (bx2 - bx1 + 1.0f) * (by2 - by1 + 1.0f);
    float best = -1.0f;
    int arg = 0;
    for (int g = 0; g < ng; g++) {
        float4 gb = sg[g];
        float iw = fminf(bx2, gb.z) - fmaxf(bx1, gb.x) + 1.0f; iw = fmaxf(iw, 0.0f);
        float ih = fminf(by2, gb.w) - fmaxf(by1, gb.y) + 1.0f; ih = fmaxf(ih, 0.0f);
        float inter = iw * ih;
        float iou = inter / (areaA + sarea[g] - inter);
        if (iou > best) { best = iou; arg = g; }   // first-max == jnp.argmax
    }
    float4 gb = sg[arg];
    float gw = gb.z - gb.x + 1.0f, gh = gb.w - gb.y + 1.0f;
    float gcx = gb.x + 0.5f * gw,  gcy = gb.y + 0.5f * gh;
    float t0 = (gcx - cx) / w, t1 = (gcy - cy) / h;
    float t2 = logf(gw / w),   t3 = logf(gh / h);

    float* o = out + (size_t)r * 10;
    o[0] = bx1; o[1] = by1; o[2] = bx2; o[3] = by2;
    o[4] = score; o[5] = 1.0f;
    o[6] = t0; o[7] = t1; o[8] = t2; o[9] = t3;
}

extern "C" void kernel_launch(void* const* d_in, const int* in_sizes, int n_in,
                              void* d_out, int out_size, void* d_ws, size_t ws_size,
                              hipStream_t stream) {
    Ptrs p;
    // setup_inputs() dict order is interleaved (anchors0, cls0, reg0, anchors1, ...).
    // Disambiguate defensively via in_sizes[2] (reg0 flat = 98304*8).
    bool interleaved = (in_sizes[2] == N0 * 8);
    for (int l = 0; l < 5; l++) {
        if (interleaved) {
            p.anc[l] = (const float*)d_in[3 * l + 0];
            p.cls[l] = (const float*)d_in[3 * l + 1];
            p.reg[l] = (const float*)d_in[3 * l + 2];
        } else {
            p.anc[l] = (const float*)d_in[l];
            p.cls[l] = (const float*)d_in[5 + l];
            p.reg[l] = (const float*)d_in[10 + l];
        }
    }
    const float* gt    = (const float*)d_in[15];
    const int*   numgt = (const int*)d_in[16];

    char* ws = (char*)d_ws;
    SelState* st = (SelState*)ws;                                          // ~2 KiB
    unsigned long long* cand = (unsigned long long*)(ws + 4096);           // 2*CAP*8 = 256 KiB
    unsigned* selIdx = (unsigned*)(ws + 4096 + 2 * (size_t)CAP * 8);       // 2*K_TOP*4

    float* out = (float*)d_out;

    k_init<<<dim3(1), dim3(256), 0, stream>>>(st);
    for (int pass = 0; pass < 4; pass++) {
        k_hist<<<dim3(64, 2), dim3(256), 0, stream>>>(p.cls[0], p.cls[1], st, pass);
        k_pick<<<dim3(2), dim3(256), 0, stream>>>(st, pass);
    }
    k_compact<<<dim3(96, 2), dim3(256), 0, stream>>>(p.cls[0], p.cls[1], st, cand);
    k_rank<<<dim3(CAP / 256, 2), dim3(256), 0, stream>>>(st, cand, selIdx);
    k_final<<<dim3((NROWS + 255) / 256), dim3(256), 0, stream>>>(p, gt, numgt, selIdx, out);
}